// Round 8
// baseline (1884.628 us; speedup 1.0000x reference)
//
#include <hip/hip_runtime.h>

// Problem dims
#define BATCH 256
#define TLEN  512
#define DIN   128
#define DFEAT 256
#define DLAT  512
#define G4    2048   // 4*DLAT
#define KCAT  768    // DFEAT + DLAT

typedef __bf16 bf16x8 __attribute__((ext_vector_type(8)));
typedef float f32x4 __attribute__((ext_vector_type(4)));

typedef __attribute__((address_space(1))) const unsigned int glb_u32;
typedef __attribute__((address_space(3))) unsigned int lds_u32;

// ws layout (bytes) -- total 68,222,976 (< proven 70.8 MB budget)
#define WENC_OFF   0u          // 128x256 bf16 frag-linear: 65,536
#define ENC_OFF    65536u      // enc bf16 [T][B][256]: 67,108,864
#define H_OFF      67174400u   // tagged h u32 [2][256][512]: 1,048,576
// tagged cell: [bf16(h) << 16 | (step & 0xffff)] -- tag travels WITH data

__device__ __forceinline__ float sigf(float x)  { return 1.0f / (1.0f + __expf(-x)); }
__device__ __forceinline__ float tanhfast(float x){ return 2.0f / (1.0f + __expf(-2.0f * x)) - 1.0f; }
__device__ __forceinline__ unsigned short bfb(float f) {
    __bf16 b = (__bf16)f;
    return __builtin_bit_cast(unsigned short, b);
}
__device__ __forceinline__ float bfu(unsigned w) {   // high 16 bits -> float
    return (float)__builtin_bit_cast(__bf16, (unsigned short)(w >> 16));
}

// ---------------------------------------------------------------------------
// Weight prep (W_enc only now): bf16 fragment-linear copy of W_enc (128x256).
// chunk c2 = ((ntg*4 + ks)*64 + l) holds B[k=ks*32+(l>>4)*8 .. +8][col],
// col = ntg*16 + (l&15).
// ---------------------------------------------------------------------------
__global__ __launch_bounds__(256) void wprep_kernel(const float* __restrict__ Wenc,
                                                    __bf16* __restrict__ wencf) {
    int c2 = blockIdx.x * 256 + threadIdx.x;   // [0, 4096)
    int ntg = c2 >> 8;
    int r = c2 & 255;
    int ks = r >> 6, l = r & 63;
    int col = ntg * 16 + (l & 15);
    int kc = ks * 32 + (l >> 4) * 8;
    bf16x8 o;
#pragma unroll
    for (int j = 0; j < 8; ++j) o[j] = (__bf16)Wenc[(kc + j) * DFEAT + col];
    *reinterpret_cast<bf16x8*>(wencf + (size_t)c2 * 8) = o;
}

// ---------------------------------------------------------------------------
// Encoder: enc[t][b][f] = tanh(x[b][t][:] @ W_enc + b_enc), bf16 out.
// ---------------------------------------------------------------------------
__global__ __launch_bounds__(256) void enc_kernel(const float* __restrict__ x,
                                                  const float* __restrict__ benc,
                                                  const __bf16* __restrict__ wencf,
                                                  __bf16* __restrict__ enc) {
    __shared__ uint4 afrag4[1024];   // 16 KB frag-linear A
    __bf16* afrag = reinterpret_cast<__bf16*>(afrag4);
    int tid = threadIdx.x;
    int lane = tid & 63, w = tid >> 6;
    int rid0 = blockIdx.x * 64;
    int ntg0 = blockIdx.y * 4;

    bf16x8 wr[4][4];
#pragma unroll
    for (int n = 0; n < 4; ++n)
#pragma unroll
        for (int ks = 0; ks < 4; ++ks)
            wr[n][ks] = *reinterpret_cast<const bf16x8*>(
                wencf + (size_t)(((ntg0 + n) * 4 + ks) * 64 + lane) * 8);
    float bias[4];
#pragma unroll
    for (int n = 0; n < 4; ++n) bias[n] = benc[(ntg0 + n) * 16 + (lane & 15)];

#pragma unroll
    for (int i = 0; i < 4; ++i) {
        int c = tid + 256 * i;          // [0,1024): row = c>>4, k8 = c&15
        int row = c >> 4, k8 = c & 15;
        const float* src = x + (size_t)(rid0 + row) * DIN + k8 * 8;
        float4 f0 = *reinterpret_cast<const float4*>(src);
        float4 f1 = *reinterpret_cast<const float4*>(src + 4);
        bf16x8 o;
        o[0] = (__bf16)f0.x; o[1] = (__bf16)f0.y; o[2] = (__bf16)f0.z; o[3] = (__bf16)f0.w;
        o[4] = (__bf16)f1.x; o[5] = (__bf16)f1.y; o[6] = (__bf16)f1.z; o[7] = (__bf16)f1.w;
        int l = (k8 & 3) * 16 + (row & 15);
        int a16 = ((row >> 4) * 4 + (k8 >> 2)) * 64 + l;
        *reinterpret_cast<bf16x8*>(afrag + (size_t)a16 * 8) = o;
    }
    __syncthreads();

    int m = w;
    f32x4 acc[4];
#pragma unroll
    for (int n = 0; n < 4; ++n) acc[n] = (f32x4){bias[n], bias[n], bias[n], bias[n]};
#pragma unroll
    for (int ks = 0; ks < 4; ++ks) {
        bf16x8 a = *reinterpret_cast<const bf16x8*>(afrag + (size_t)((m * 4 + ks) * 64 + lane) * 8);
#pragma unroll
        for (int n = 0; n < 4; ++n)
            acc[n] = __builtin_amdgcn_mfma_f32_16x16x32_bf16(a, wr[n][ks], acc[n], 0, 0, 0);
    }
#pragma unroll
    for (int n = 0; n < 4; ++n) {
        int colg = (ntg0 + n) * 16 + (lane & 15);
#pragma unroll
        for (int q = 0; q < 4; ++q) {
            int rid = rid0 + m * 16 + (lane >> 4) * 4 + q;
            int bb = rid >> 9, tt = rid & 511;
            float th = tanhfast(acc[n][q]);
            enc[(size_t)(tt * BATCH + bb) * DFEAT + colg] = (__bf16)th;
        }
    }
}

// ---------------------------------------------------------------------------
// Persistent LSTM, 16 groups x 16 wgs, TAGGED POLL-ON-DATA exchange.
// h cell = u32 [bf16<<16 | tag16], tag = step index the h belongs to.
// The h store IS the release (tag+data atomic in one word, relaxed sc1 to
// LLC); consumers poll their own chunk words until all tags == t (one LLC
// hop = detect + data). Double-parity + tag induction: parity-t slots are
// only overwritten (tag t+2) after every wg published t+1, which required
// consuming t. No flags, no fences, no drains. Weights gathered once from
// fp32 W_x/W_h directly into VGPRs (wcat eliminated to fit tagged h in ws).
// ---------------------------------------------------------------------------
__global__ __launch_bounds__(256, 1) void lstm_kernel(const __bf16* __restrict__ enc,
                                                      const float* __restrict__ Wx,
                                                      const float* __restrict__ Wh,
                                                      const float* __restrict__ blstm,
                                                      unsigned* __restrict__ hbuf) {
    extern __shared__ char smem[];
    __bf16* afrag = reinterpret_cast<__bf16*>(smem);       // 24576 B: 1536 chunks
    float* zbuf = reinterpret_cast<float*>(smem + 24576);  // 8192 B: [4][16][32]

    const int tid = threadIdx.x;
    const int lane = tid & 63, np = tid >> 6;   // np = wave = gate
    const int grp = blockIdx.x & 15, widx = blockIdx.x >> 4;
    const int b0 = grp * 16;

    // persistent weight frags gathered straight from fp32 (one-time)
    bf16x8 wreg[2][24];
#pragma unroll
    for (int nt2 = 0; nt2 < 2; ++nt2) {
        const int col = np * 512 + widx * 32 + nt2 * 16 + (lane & 15);
#pragma unroll
        for (int ks = 0; ks < 24; ++ks) {
            const int kb = ks * 32 + (lane >> 4) * 8;
            bf16x8 f;
#pragma unroll
            for (int j = 0; j < 8; ++j) {
                int kk = kb + j;
                float w = (kk < DFEAT) ? Wx[(size_t)kk * G4 + col]
                                       : Wh[(size_t)(kk - DFEAT) * G4 + col];
                f[j] = (__bf16)w;
            }
            wreg[nt2][ks] = f;
        }
    }
    const float bias0 = blstm[np * 512 + widx * 32 + (lane & 15)];
    const float bias1 = blstm[np * 512 + widx * 32 + 16 + (lane & 15)];

    // ---- hoisted loop-invariant addresses ----
    const int row = tid & 15;                                 // staging row
    const int kq = (tid >> 6) * 32 + ((tid >> 4) & 3) * 8;    // 8-col base in 128-quarter
    const __bf16* encp = enc + (size_t)(b0 + row) * DFEAT + kq;
    const unsigned* hpA = hbuf + (size_t)(b0 + row) * DLAT + kq;        // parity 0
    const unsigned* hpB = hpA + (size_t)BATCH * DLAT;                   // parity 1
    __bf16* enc_lds = afrag + tid * 8;          // enc chunk; second at +2048 elems
    __bf16* h_lds = afrag + (512 + tid) * 8;    // h chunk ii=0; +2048 elems per ii
    const int cell = 2 * tid;
    const int crow = cell >> 5, ccol = cell & 31;
    unsigned long long* hd0 = reinterpret_cast<unsigned long long*>(
        hbuf + (size_t)(b0 + crow) * DLAT + widx * 32 + ccol);          // parity 0
    unsigned long long* hd1 = reinterpret_cast<unsigned long long*>(
        hbuf + (size_t)BATCH * DLAT + (size_t)(b0 + crow) * DLAT + widx * 32 + ccol);
    const float* zg = zbuf + crow * 32 + ccol;                // + g*512 per gate
    float* zst = zbuf + np * 512 + ((lane >> 4) * 4) * 32 + (lane & 15);
    const __bf16* abase = afrag + lane * 8;                   // + ks*512 per ks

    float c0 = 0.f, c1 = 0.f;

    // prologue: stage enc(0) direct to LDS; tail barrier drains vmcnt
    __builtin_amdgcn_global_load_lds((glb_u32*)encp, (lds_u32*)enc_lds, 16, 0, 0);
    __builtin_amdgcn_global_load_lds((glb_u32*)(encp + 128), (lds_u32*)(enc_lds + 2048), 16, 0, 0);
    encp += (size_t)BATCH * DFEAT;
    __syncthreads();

#pragma unroll 1
    for (int t = 0; t < TLEN; ++t) {
        // (1) enc-part MFMAs (ks 0..7) -- h-independent, overlaps peer lateness
        f32x4 acc0 = (f32x4){bias0, bias0, bias0, bias0};
        f32x4 acc1 = (f32x4){bias1, bias1, bias1, bias1};
#pragma unroll
        for (int ks = 0; ks < 8; ++ks) {
            bf16x8 a = *reinterpret_cast<const bf16x8*>(abase + ks * 512);
            acc0 = __builtin_amdgcn_mfma_f32_16x16x32_bf16(a, wreg[0][ks], acc0, 0, 0, 0);
            acc1 = __builtin_amdgcn_mfma_f32_16x16x32_bf16(a, wreg[1][ks], acc1, 0, 0, 0);
        }

        if (t > 0) {
            // (2) poll-on-data: each thread polls ITS 4 chunks (8 cells each)
            //     until all tags == t, then extracts bf16 pairs into LDS.
            const unsigned tlo = (unsigned)t & 0xffffu;
            const unsigned* hp = (t & 1) ? hpB : hpA;
#pragma unroll
            for (int ii = 0; ii < 4; ++ii) {
                const unsigned* p = hp + ii * 128;
                uint4 a, b;
                for (;;) {
                    asm volatile(
                        "global_load_dwordx4 %0, %2, off sc1\n\t"
                        "global_load_dwordx4 %1, %2, off offset:16 sc1\n\t"
                        "s_waitcnt vmcnt(0)"
                        : "=&v"(a), "=&v"(b) : "v"(p) : "memory");
                    unsigned m = ((a.x ^ tlo) | (a.y ^ tlo) | (a.z ^ tlo) | (a.w ^ tlo) |
                                  (b.x ^ tlo) | (b.y ^ tlo) | (b.z ^ tlo) | (b.w ^ tlo)) & 0xffffu;
                    if (m == 0) break;
                    __builtin_amdgcn_s_sleep(1);
                }
                uint4 o;
                o.x = (a.x >> 16) | (a.y & 0xffff0000u);
                o.y = (a.z >> 16) | (a.w & 0xffff0000u);
                o.z = (b.x >> 16) | (b.y & 0xffff0000u);
                o.w = (b.z >> 16) | (b.w & 0xffff0000u);
                *reinterpret_cast<uint4*>(h_lds + ii * 2048) = o;
            }
            __syncthreads();   // b2: h frags visible block-wide

            // (3) h-part MFMAs (ks 8..23)
#pragma unroll
            for (int ks = 8; ks < 24; ++ks) {
                bf16x8 a = *reinterpret_cast<const bf16x8*>(abase + ks * 512);
                acc0 = __builtin_amdgcn_mfma_f32_16x16x32_bf16(a, wreg[0][ks], acc0, 0, 0, 0);
                acc1 = __builtin_amdgcn_mfma_f32_16x16x32_bf16(a, wreg[1][ks], acc1, 0, 0, 0);
            }
        }

        // (4) z exchange via LDS
#pragma unroll
        for (int q = 0; q < 4; ++q) {
            zst[q * 32] = acc0[q];
            zst[q * 32 + 16] = acc1[q];
        }
        __syncthreads();   // b3

        // (5) gates + state update (2 adjacent cells per thread) + tagged store
        float2 zi = *reinterpret_cast<const float2*>(zg);
        float2 zf = *reinterpret_cast<const float2*>(zg + 512);
        float2 zgt = *reinterpret_cast<const float2*>(zg + 1024);
        float2 zo = *reinterpret_cast<const float2*>(zg + 1536);
        float i0 = sigf(zi.x), f0 = sigf(zf.x), g0 = tanhfast(zgt.x), o0 = sigf(zo.x);
        c0 = f0 * c0 + i0 * g0;
        float h0 = o0 * tanhfast(c0);
        float i1 = sigf(zi.y), f1 = sigf(zf.y), g1 = tanhfast(zgt.y), o1 = sigf(zo.y);
        c1 = f1 * c1 + i1 * g1;
        float h1 = o1 * tanhfast(c1);

        const unsigned tago = (unsigned)(t + 1) & 0xffffu;
        unsigned w0 = ((unsigned)bfb(h0) << 16) | tago;
        unsigned w1 = ((unsigned)bfb(h1) << 16) | tago;
        unsigned long long pk = (unsigned long long)w0 | ((unsigned long long)w1 << 32);
        // the store IS the release: tag+data in the same words, straight to LLC
        __hip_atomic_store(((t & 1) ? hd0 : hd1), pk, __ATOMIC_RELAXED,
                           __HIP_MEMORY_SCOPE_AGENT);

        // (6) prefetch enc(t+1) to LDS; tail barrier drains vmcnt
        if (t + 1 < TLEN) {
            __builtin_amdgcn_global_load_lds((glb_u32*)encp, (lds_u32*)enc_lds, 16, 0, 0);
            __builtin_amdgcn_global_load_lds((glb_u32*)(encp + 128),
                                             (lds_u32*)(enc_lds + 2048), 16, 0, 0);
            encp += (size_t)BATCH * DFEAT;
        }
        __syncthreads();   // b4 (tail)
    }
}

// ---------------------------------------------------------------------------
// Decoder: out[b] = h_last[b,:] @ W_dec + b_dec. h(512) is tagged parity 0.
// ---------------------------------------------------------------------------
__global__ __launch_bounds__(64) void dec_kernel(const unsigned* __restrict__ hbuf,
                                                 const float* __restrict__ wdec,
                                                 const float* __restrict__ bdec,
                                                 float* __restrict__ out) {
    int b = blockIdx.x, lane = threadIdx.x;
    const unsigned* hrow = hbuf + (size_t)b * DLAT + lane * 8;
    uint4 a = *reinterpret_cast<const uint4*>(hrow);
    uint4 c = *reinterpret_cast<const uint4*>(hrow + 4);
    float4 w0 = *reinterpret_cast<const float4*>(wdec + lane * 8);
    float4 w1 = *reinterpret_cast<const float4*>(wdec + lane * 8 + 4);
    float s = bfu(a.x) * w0.x + bfu(a.y) * w0.y + bfu(a.z) * w0.z + bfu(a.w) * w0.w +
              bfu(c.x) * w1.x + bfu(c.y) * w1.y + bfu(c.z) * w1.z + bfu(c.w) * w1.w;
#pragma unroll
    for (int off = 32; off; off >>= 1) s += __shfl_xor(s, off);
    if (lane == 0) out[b] = s + bdec[0];
}

extern "C" void kernel_launch(void* const* d_in, const int* in_sizes, int n_in,
                              void* d_out, int out_size, void* d_ws, size_t ws_size,
                              hipStream_t stream) {
    (void)in_sizes; (void)n_in; (void)out_size; (void)ws_size;
    const float* x     = (const float*)d_in[0];
    const float* Wenc  = (const float*)d_in[1];
    const float* benc  = (const float*)d_in[2];
    const float* Wx    = (const float*)d_in[3];
    const float* Wh    = (const float*)d_in[4];
    const float* blstm = (const float*)d_in[5];
    const float* Wdec  = (const float*)d_in[6];
    const float* bdec  = (const float*)d_in[7];

    char* ws = (char*)d_ws;
    __bf16* wencf = (__bf16*)(ws + WENC_OFF);
    __bf16* enc   = (__bf16*)(ws + ENC_OFF);
    unsigned* hbuf = (unsigned*)(ws + H_OFF);

    // clear tags each call (stale same-tag data from a previous replay races)
    (void)hipMemsetAsync(ws + H_OFF, 0, 1048576, stream);

    wprep_kernel<<<16, 256, 0, stream>>>(Wenc, wencf);
    enc_kernel<<<dim3(2048, 4), 256, 0, stream>>>(x, benc, wencf, enc);

    // 90 KB dynamic LDS forces 1 block/CU (256 blocks on 256 CUs).
    (void)hipFuncSetAttribute(reinterpret_cast<const void*>(lstm_kernel),
                              hipFuncAttributeMaxDynamicSharedMemorySize, 90112);
    lstm_kernel<<<256, 256, 90112, stream>>>(enc, Wx, Wh, blstm, hbuf);

    dec_kernel<<<256, 64, 0, stream>>>(hbuf, Wdec, bdec, (float*)d_out);
}

// Round 9
// 1501.365 us; speedup vs baseline: 1.2553x; 1.2553x over previous
//
#include <hip/hip_runtime.h>

// Problem dims
#define BATCH 256
#define TLEN  512
#define DIN   128
#define DFEAT 256
#define DLAT  512
#define G4    2048   // 4*DLAT
#define KCAT  768    // DFEAT + DLAT

typedef __bf16 bf16x8 __attribute__((ext_vector_type(8)));
typedef float f32x4 __attribute__((ext_vector_type(4)));

// ws layout (bytes) -- identical to round 6 (proven)
#define WCAT_OFF   0u          // 768x2048 bf16 frag-linear: 3,145,728
#define WENC_OFF   3145728u    // 128x256  bf16 frag-linear: 65,536
#define ENC_OFF    3211264u    // enc bf16 [T][B][256]: 67,108,864
#define H_OFF      70320128u   // h dbuf bf16 [2][256][512]: 524,288
#define FLAG_OFF   70844416u   // flags: (grp*16+widx)*16 uints (64B apart): 16,384

__device__ __forceinline__ float sigf(float x)  { return 1.0f / (1.0f + __expf(-x)); }
__device__ __forceinline__ float tanhfast(float x){ return 2.0f / (1.0f + __expf(-2.0f * x)) - 1.0f; }
__device__ __forceinline__ unsigned short bfb(float f) {
    __bf16 b = (__bf16)f;
    return __builtin_bit_cast(unsigned short, b);
}

// ---------------------------------------------------------------------------
// Weight prep: bf16 fragment-linear copies of [W_x;W_h] (768x2048) and W_enc.
// NEW wcat layout (wave-owns-all-gates): chunk cid = ((((widx*4 + np)*2 + nf)
// *24 + ks)*64 + l) holds B[k = ks*32+(l>>4)*8 .. +8][col] with
//   cc = l&15;  gate = (cc<8) ? (nf?2:0) : (nf?3:1);
//   col = gate*512 + widx*32 + np*8 + (cc&7).
// So frag nf=0 outputs [i(8 cols)|f(8 cols)], nf=1 outputs [g|o] for the
// wave's 8 h-columns -- all 4 gates of a cell land within one wave.
// ---------------------------------------------------------------------------
__global__ __launch_bounds__(256) void wprep_kernel(const float* __restrict__ Wx,
                                                    const float* __restrict__ Wh,
                                                    const float* __restrict__ Wenc,
                                                    __bf16* __restrict__ wcat,
                                                    __bf16* __restrict__ wencf) {
    int cid = blockIdx.x * 256 + threadIdx.x;   // 200704 total
    float v[8];
    __bf16* dst;
    if (cid < 196608) {
        int widx = cid / 12288;      // 16 wgs
        int r1 = cid % 12288;
        int nn = r1 / 1536;          // np*2 + nf, 0..7
        int r2 = r1 % 1536;
        int ks = r2 >> 6, l = r2 & 63;
        int np = nn >> 1, nf = nn & 1;
        int cc = l & 15;
        int gate = (cc < 8) ? (nf ? 2 : 0) : (nf ? 3 : 1);
        int col = gate * 512 + widx * 32 + np * 8 + (cc & 7);
        int kc = ks * 32 + (l >> 4) * 8;
#pragma unroll
        for (int j = 0; j < 8; ++j) {
            int kk = kc + j;
            v[j] = (kk < DFEAT) ? Wx[kk * G4 + col] : Wh[(kk - DFEAT) * G4 + col];
        }
        dst = wcat + (size_t)cid * 8;
    } else {
        int c2 = cid - 196608;   // [0, 4096)
        int ntg = c2 >> 8;
        int r = c2 & 255;
        int ks = r >> 6, l = r & 63;
        int col = ntg * 16 + (l & 15);
        int kc = ks * 32 + (l >> 4) * 8;
#pragma unroll
        for (int j = 0; j < 8; ++j) v[j] = Wenc[(kc + j) * DFEAT + col];
        dst = wencf + (size_t)c2 * 8;
    }
    bf16x8 o;
#pragma unroll
    for (int j = 0; j < 8; ++j) o[j] = (__bf16)v[j];
    *reinterpret_cast<bf16x8*>(dst) = o;
}

// ---------------------------------------------------------------------------
// Encoder: enc[t][b][f] = tanh(x[b][t][:] @ W_enc + b_enc), bf16 out.
// ---------------------------------------------------------------------------
__global__ __launch_bounds__(256) void enc_kernel(const float* __restrict__ x,
                                                  const float* __restrict__ benc,
                                                  const __bf16* __restrict__ wencf,
                                                  __bf16* __restrict__ enc) {
    __shared__ uint4 afrag4[1024];   // 16 KB frag-linear A
    __bf16* afrag = reinterpret_cast<__bf16*>(afrag4);
    int tid = threadIdx.x;
    int lane = tid & 63, w = tid >> 6;
    int rid0 = blockIdx.x * 64;
    int ntg0 = blockIdx.y * 4;

    bf16x8 wr[4][4];
#pragma unroll
    for (int n = 0; n < 4; ++n)
#pragma unroll
        for (int ks = 0; ks < 4; ++ks)
            wr[n][ks] = *reinterpret_cast<const bf16x8*>(
                wencf + (size_t)(((ntg0 + n) * 4 + ks) * 64 + lane) * 8);
    float bias[4];
#pragma unroll
    for (int n = 0; n < 4; ++n) bias[n] = benc[(ntg0 + n) * 16 + (lane & 15)];

#pragma unroll
    for (int i = 0; i < 4; ++i) {
        int c = tid + 256 * i;          // [0,1024): row = c>>4, k8 = c&15
        int row = c >> 4, k8 = c & 15;
        const float* src = x + (size_t)(rid0 + row) * DIN + k8 * 8;
        float4 f0 = *reinterpret_cast<const float4*>(src);
        float4 f1 = *reinterpret_cast<const float4*>(src + 4);
        bf16x8 o;
        o[0] = (__bf16)f0.x; o[1] = (__bf16)f0.y; o[2] = (__bf16)f0.z; o[3] = (__bf16)f0.w;
        o[4] = (__bf16)f1.x; o[5] = (__bf16)f1.y; o[6] = (__bf16)f1.z; o[7] = (__bf16)f1.w;
        int l = (k8 & 3) * 16 + (row & 15);
        int a16 = ((row >> 4) * 4 + (k8 >> 2)) * 64 + l;
        *reinterpret_cast<bf16x8*>(afrag + (size_t)a16 * 8) = o;
    }
    __syncthreads();

    int m = w;
    f32x4 acc[4];
#pragma unroll
    for (int n = 0; n < 4; ++n) acc[n] = (f32x4){bias[n], bias[n], bias[n], bias[n]};
#pragma unroll
    for (int ks = 0; ks < 4; ++ks) {
        bf16x8 a = *reinterpret_cast<const bf16x8*>(afrag + (size_t)((m * 4 + ks) * 64 + lane) * 8);
#pragma unroll
        for (int n = 0; n < 4; ++n)
            acc[n] = __builtin_amdgcn_mfma_f32_16x16x32_bf16(a, wr[n][ks], acc[n], 0, 0, 0);
    }
#pragma unroll
    for (int n = 0; n < 4; ++n) {
        int colg = (ntg0 + n) * 16 + (lane & 15);
#pragma unroll
        for (int q = 0; q < 4; ++q) {
            int rid = rid0 + m * 16 + (lane >> 4) * 4 + q;
            int bb = rid >> 9, tt = rid & 511;
            float th = tanhfast(acc[n][q]);
            enc[(size_t)(tt * BATCH + bb) * DFEAT + colg] = (__bf16)th;
        }
    }
}

// ---------------------------------------------------------------------------
// Persistent LSTM, 16 groups x 16 wgs (r6-proven geometry + protocol).
// Round-9 change (only one): wave-owns-all-gates B layout -> the z-exchange
// (zbuf LDS + barrier) is GONE. After its MFMAs each wave holds i|f (acc0)
// and g|o (acc1) for its own 8 h-cols; 9 __shfl_xor ops deliver all 4 gates
// per cell in-thread, one more shfl re-pairs adjacent columns so the h store
// stays one 4B relaxed-agent (sc1) store per thread (r6-proven primitive).
// Barriers 5 -> 4 per step; gates+store move ~300-500cy earlier on the
// producer link of the inter-block chain.
// ---------------------------------------------------------------------------
__global__ __launch_bounds__(256, 1) void lstm_kernel(const __bf16* __restrict__ enc,
                                                      const __bf16* __restrict__ wcat,
                                                      const float* __restrict__ blstm,
                                                      __bf16* __restrict__ hbuf,
                                                      unsigned int* __restrict__ flags) {
    extern __shared__ char smem[];
    __bf16* afrag = reinterpret_cast<__bf16*>(smem);       // 24576 B: 1536 chunks

    int tid = threadIdx.x;
    int lane = tid & 63, np = tid >> 6;     // np = wave; owns 8 h-cols, all gates
    int grp = blockIdx.x & 15, widx = blockIdx.x >> 4;
    int b0 = grp * 16;
    unsigned int* myflag = &flags[(grp * 16 + widx) * 16];

    // persistent weight frags: nf=0 -> [i|f], nf=1 -> [g|o]
    bf16x8 wreg[2][24];
#pragma unroll
    for (int nf = 0; nf < 2; ++nf)
#pragma unroll
        for (int ks = 0; ks < 24; ++ks)
            wreg[nf][ks] = *reinterpret_cast<const bf16x8*>(
                wcat + (size_t)(((((widx * 4 + np) * 2 + nf) * 24) + ks) * 64 + lane) * 8);

    const int cbase = widx * 32 + np * 8 + (lane & 7);
    const bool lo = (lane & 15) < 8;
    const float bias0 = blstm[(lo ? 0 : 1) * 512 + cbase];   // i or f col bias
    const float bias1 = blstm[(lo ? 2 : 3) * 512 + cbase];   // g or o col bias

    // cell state: thread owns 2 cells, rows (g4, g4+1) [lo] or (g4+2, g4+3),
    // same column cbase. Store pairing via lane^1 -> one 4B store per thread.
    float c0 = 0.f, c1 = 0.f;
    const int srow = (lane >> 4) * 4 + (lo ? 0 : 2) + (lane & 1);
    const int scol = widx * 32 + np * 8 + (lane & 6);
    unsigned* hdA = reinterpret_cast<unsigned*>(
        hbuf + (size_t)(b0 + srow) * DLAT + scol);                        // parity 0
    unsigned* hdB = reinterpret_cast<unsigned*>(
        hbuf + (size_t)BATCH * DLAT + (size_t)(b0 + srow) * DLAT + scol); // parity 1

#pragma unroll 1
    for (int t = 0; t < TLEN; ++t) {
        // (1) stage enc_t chunks (ks 0..7): c in [0,512), 2 per thread
#pragma unroll
        for (int i = 0; i < 2; ++i) {
            int c = tid + 256 * i;
            int ks = c >> 6, l = c & 63;
            int row = l & 15;
            int k = ks * 32 + (l >> 4) * 8;
            uint4 d = *reinterpret_cast<const uint4*>(
                enc + (size_t)(t * BATCH + b0 + row) * DFEAT + k);
            *reinterpret_cast<uint4*>(afrag + (size_t)c * 8) = d;
        }
        __syncthreads();   // b1

        // (2) enc-part MFMAs (ks 0..7) -- h-independent, before the poll
        f32x4 acc0 = (f32x4){bias0, bias0, bias0, bias0};
        f32x4 acc1 = (f32x4){bias1, bias1, bias1, bias1};
#pragma unroll
        for (int ks = 0; ks < 8; ++ks) {
            bf16x8 a = *reinterpret_cast<const bf16x8*>(
                afrag + (size_t)((ks * 64 + lane) * 8));
            acc0 = __builtin_amdgcn_mfma_f32_16x16x32_bf16(a, wreg[0][ks], acc0, 0, 0, 0);
            acc1 = __builtin_amdgcn_mfma_f32_16x16x32_bf16(a, wreg[1][ks], acc1, 0, 0, 0);
        }

        if (t > 0) {
            // (3) acquire: wave 0 polls the group's 16 flags (r6-proven)
            if (tid < 64) {
                const unsigned int* f = &flags[(grp * 16 + (lane & 15)) * 16];
                unsigned v;
                do {
                    v = __hip_atomic_load(f, __ATOMIC_RELAXED, __HIP_MEMORY_SCOPE_AGENT);
                } while (!__all((int)(v >= (unsigned)t)));
            }
            __syncthreads();   // b2

            // (4) stage h(t) slice (ks 8..23): c in [512,1536), 4 per thread,
            //     batched 16B sc1 loads (vector OUTPUTS only in asm)
            {
                const __bf16* hsrc = hbuf + (size_t)(t & 1) * (BATCH * DLAT);
                const __bf16* src[4];
                int cdst[4];
#pragma unroll
                for (int ii = 0; ii < 4; ++ii) {
                    int c = tid + 256 * (ii + 2);
                    int ks = c >> 6, l = c & 63;
                    int row = l & 15;
                    int kh = ks * 32 + (l >> 4) * 8 - DFEAT;
                    src[ii] = hsrc + (size_t)(b0 + row) * DLAT + kh;
                    cdst[ii] = c;
                }
                uint4 d0, d1, d2, d3;
                asm volatile(
                    "global_load_dwordx4 %0, %4, off sc1\n\t"
                    "global_load_dwordx4 %1, %5, off sc1\n\t"
                    "global_load_dwordx4 %2, %6, off sc1\n\t"
                    "global_load_dwordx4 %3, %7, off sc1\n\t"
                    "s_waitcnt vmcnt(0)"
                    : "=&v"(d0), "=&v"(d1), "=&v"(d2), "=&v"(d3)
                    : "v"(src[0]), "v"(src[1]), "v"(src[2]), "v"(src[3])
                    : "memory");
                *reinterpret_cast<uint4*>(afrag + (size_t)cdst[0] * 8) = d0;
                *reinterpret_cast<uint4*>(afrag + (size_t)cdst[1] * 8) = d1;
                *reinterpret_cast<uint4*>(afrag + (size_t)cdst[2] * 8) = d2;
                *reinterpret_cast<uint4*>(afrag + (size_t)cdst[3] * 8) = d3;
            }
            __syncthreads();   // b3

            // (5) h-part MFMAs (ks 8..23)
#pragma unroll
            for (int ks = 8; ks < 24; ++ks) {
                bf16x8 a = *reinterpret_cast<const bf16x8*>(
                    afrag + (size_t)((ks * 64 + lane) * 8));
                acc0 = __builtin_amdgcn_mfma_f32_16x16x32_bf16(a, wreg[0][ks], acc0, 0, 0, 0);
                acc1 = __builtin_amdgcn_mfma_f32_16x16x32_bf16(a, wreg[1][ks], acc1, 0, 0, 0);
            }
        }

        // (6) in-wave gate exchange: lanes cc and cc^8 hold (i,g) / (f,o) for
        // the same cells. 8 shfl_xor(8) deliver the missing gates; lower lane
        // handles q=0,1 (rows g4,g4+1), upper q=2,3 (rows g4+2,g4+3).
        float p00 = __shfl_xor(acc0[0], 8), p01 = __shfl_xor(acc0[1], 8);
        float p02 = __shfl_xor(acc0[2], 8), p03 = __shfl_xor(acc0[3], 8);
        float p10 = __shfl_xor(acc1[0], 8), p11 = __shfl_xor(acc1[1], 8);
        float p12 = __shfl_xor(acc1[2], 8), p13 = __shfl_xor(acc1[3], 8);

        float zi_a = lo ? acc0[0] : p02, zf_a = lo ? p00 : acc0[2];
        float zg_a = lo ? acc1[0] : p12, zo_a = lo ? p10 : acc1[2];
        float zi_b = lo ? acc0[1] : p03, zf_b = lo ? p01 : acc0[3];
        float zg_b = lo ? acc1[1] : p13, zo_b = lo ? p11 : acc1[3];

        float ia = sigf(zi_a), fa = sigf(zf_a), ga = tanhfast(zg_a), oa = sigf(zo_a);
        c0 = fa * c0 + ia * ga;
        float h_a = oa * tanhfast(c0);
        float ib = sigf(zi_b), fb = sigf(zf_b), gb = tanhfast(zg_b), ob = sigf(zo_b);
        c1 = fb * c1 + ib * gb;
        float h_b = ob * tanhfast(c1);

        // (7) re-pair adjacent columns via lane^1 -> one 4B word per thread:
        // even lane: row r_a, cols (c, c+1); odd lane: row r_b, cols (c-1, c)
        unsigned sendv = (lane & 1) ? (unsigned)bfb(h_a) : (unsigned)bfb(h_b);
        unsigned recv = (unsigned)__shfl_xor((int)sendv, 1);
        unsigned word = (lane & 1) ? (recv | ((unsigned)bfb(h_b) << 16))
                                   : ((unsigned)bfb(h_a) | (recv << 16));
        __hip_atomic_store(((t & 1) ? hdA : hdB), word, __ATOMIC_RELAXED,
                           __HIP_MEMORY_SCOPE_AGENT);

        // (8) release: __syncthreads drains each wave's vmcnt(0) -> stores
        // LLC-visible; then publish own flag (independent line per wg).
        __syncthreads();   // b4
        if (tid == 0)
            __hip_atomic_store(myflag, (unsigned int)(t + 1), __ATOMIC_RELAXED,
                               __HIP_MEMORY_SCOPE_AGENT);
    }
}

// ---------------------------------------------------------------------------
// Decoder: out[b] = h_last[b,:] @ W_dec + b_dec. h_last is hbuf[0] (T even).
// ---------------------------------------------------------------------------
__global__ __launch_bounds__(64) void dec_kernel(const __bf16* __restrict__ hbuf,
                                                 const float* __restrict__ wdec,
                                                 const float* __restrict__ bdec,
                                                 float* __restrict__ out) {
    int b = blockIdx.x, lane = threadIdx.x;
    uint4 d = *reinterpret_cast<const uint4*>(hbuf + (size_t)b * DLAT + lane * 8);
    const __bf16* hv = reinterpret_cast<const __bf16*>(&d);
    float4 w0 = *reinterpret_cast<const float4*>(wdec + lane * 8);
    float4 w1 = *reinterpret_cast<const float4*>(wdec + lane * 8 + 4);
    float s = (float)hv[0] * w0.x + (float)hv[1] * w0.y + (float)hv[2] * w0.z +
              (float)hv[3] * w0.w + (float)hv[4] * w1.x + (float)hv[5] * w1.y +
              (float)hv[6] * w1.z + (float)hv[7] * w1.w;
#pragma unroll
    for (int off = 32; off; off >>= 1) s += __shfl_xor(s, off);
    if (lane == 0) out[b] = s + bdec[0];
}

extern "C" void kernel_launch(void* const* d_in, const int* in_sizes, int n_in,
                              void* d_out, int out_size, void* d_ws, size_t ws_size,
                              hipStream_t stream) {
    (void)in_sizes; (void)n_in; (void)out_size; (void)ws_size;
    const float* x     = (const float*)d_in[0];
    const float* Wenc  = (const float*)d_in[1];
    const float* benc  = (const float*)d_in[2];
    const float* Wx    = (const float*)d_in[3];
    const float* Wh    = (const float*)d_in[4];
    const float* blstm = (const float*)d_in[5];
    const float* Wdec  = (const float*)d_in[6];
    const float* bdec  = (const float*)d_in[7];

    char* ws = (char*)d_ws;
    __bf16* wcat  = (__bf16*)(ws + WCAT_OFF);
    __bf16* wencf = (__bf16*)(ws + WENC_OFF);
    __bf16* enc   = (__bf16*)(ws + ENC_OFF);
    __bf16* hbuf  = (__bf16*)(ws + H_OFF);
    unsigned int* flags = (unsigned int*)(ws + FLAG_OFF);

    // zero the per-wg flags each call (deterministic across graph replays)
    (void)hipMemsetAsync(ws + FLAG_OFF, 0, 16384, stream);

    wprep_kernel<<<784, 256, 0, stream>>>(Wx, Wh, Wenc, wcat, wencf);
    enc_kernel<<<dim3(2048, 4), 256, 0, stream>>>(x, benc, wencf, enc);

    // 90 KB dynamic LDS forces 1 block/CU (256 blocks on 256 CUs).
    (void)hipFuncSetAttribute(reinterpret_cast<const void*>(lstm_kernel),
                              hipFuncAttributeMaxDynamicSharedMemorySize, 90112);
    lstm_kernel<<<256, 256, 90112, stream>>>(enc, wcat, blstm, hbuf, flags);

    dec_kernel<<<256, 64, 0, stream>>>(hbuf, Wdec, bdec, (float*)d_out);
}

// Round 10
// 1272.854 us; speedup vs baseline: 1.4806x; 1.1795x over previous
//
#include <hip/hip_runtime.h>

// Problem dims
#define BATCH 256
#define TLEN  512
#define DIN   128
#define DFEAT 256
#define DLAT  512
#define G4    2048   // 4*DLAT
#define KCAT  768    // DFEAT + DLAT

typedef __bf16 bf16x8 __attribute__((ext_vector_type(8)));
typedef float f32x4 __attribute__((ext_vector_type(4)));

// ws layout (bytes) -- identical to round 6/9 (proven)
#define WCAT_OFF   0u          // 768x2048 bf16 frag-linear: 3,145,728
#define WENC_OFF   3145728u    // 128x256  bf16 frag-linear: 65,536
#define ENC_OFF    3211264u    // enc bf16 [T][B][256]: 67,108,864
#define H_OFF      70320128u   // h dbuf bf16 [2][256][512]: 524,288
#define FLAG_OFF   70844416u   // flags: (grp*16+widx)*16 uints (64B apart): 16,384

__device__ __forceinline__ float sigf(float x)  { return 1.0f / (1.0f + __expf(-x)); }
__device__ __forceinline__ float tanhfast(float x){ return 2.0f / (1.0f + __expf(-2.0f * x)) - 1.0f; }
__device__ __forceinline__ unsigned short bfb(float f) {
    __bf16 b = (__bf16)f;
    return __builtin_bit_cast(unsigned short, b);
}

// ---------------------------------------------------------------------------
// Weight prep: bf16 fragment-linear copies of [W_x;W_h] (768x2048) and W_enc.
// wcat layout (wave-owns-all-gates, r9-proven): chunk cid = ((((widx*4 + np)
// *2 + nf)*24 + ks)*64 + l) holds B[k = ks*32+(l>>4)*8 .. +8][col] with
//   cc = l&15;  gate = (cc<8) ? (nf?2:0) : (nf?3:1);
//   col = gate*512 + widx*32 + np*8 + (cc&7).
// ---------------------------------------------------------------------------
__global__ __launch_bounds__(256) void wprep_kernel(const float* __restrict__ Wx,
                                                    const float* __restrict__ Wh,
                                                    const float* __restrict__ Wenc,
                                                    __bf16* __restrict__ wcat,
                                                    __bf16* __restrict__ wencf) {
    int cid = blockIdx.x * 256 + threadIdx.x;   // 200704 total
    float v[8];
    __bf16* dst;
    if (cid < 196608) {
        int widx = cid / 12288;      // 16 wgs
        int r1 = cid % 12288;
        int nn = r1 / 1536;          // np*2 + nf, 0..7
        int r2 = r1 % 1536;
        int ks = r2 >> 6, l = r2 & 63;
        int np = nn >> 1, nf = nn & 1;
        int cc = l & 15;
        int gate = (cc < 8) ? (nf ? 2 : 0) : (nf ? 3 : 1);
        int col = gate * 512 + widx * 32 + np * 8 + (cc & 7);
        int kc = ks * 32 + (l >> 4) * 8;
#pragma unroll
        for (int j = 0; j < 8; ++j) {
            int kk = kc + j;
            v[j] = (kk < DFEAT) ? Wx[kk * G4 + col] : Wh[(kk - DFEAT) * G4 + col];
        }
        dst = wcat + (size_t)cid * 8;
    } else {
        int c2 = cid - 196608;   // [0, 4096)
        int ntg = c2 >> 8;
        int r = c2 & 255;
        int ks = r >> 6, l = r & 63;
        int col = ntg * 16 + (l & 15);
        int kc = ks * 32 + (l >> 4) * 8;
#pragma unroll
        for (int j = 0; j < 8; ++j) v[j] = Wenc[(kc + j) * DFEAT + col];
        dst = wencf + (size_t)c2 * 8;
    }
    bf16x8 o;
#pragma unroll
    for (int j = 0; j < 8; ++j) o[j] = (__bf16)v[j];
    *reinterpret_cast<bf16x8*>(dst) = o;
}

// ---------------------------------------------------------------------------
// Encoder: enc[t][b][f] = tanh(x[b][t][:] @ W_enc + b_enc), bf16 out.
// ---------------------------------------------------------------------------
__global__ __launch_bounds__(256) void enc_kernel(const float* __restrict__ x,
                                                  const float* __restrict__ benc,
                                                  const __bf16* __restrict__ wencf,
                                                  __bf16* __restrict__ enc) {
    __shared__ uint4 afrag4[1024];   // 16 KB frag-linear A
    __bf16* afrag = reinterpret_cast<__bf16*>(afrag4);
    int tid = threadIdx.x;
    int lane = tid & 63, w = tid >> 6;
    int rid0 = blockIdx.x * 64;
    int ntg0 = blockIdx.y * 4;

    bf16x8 wr[4][4];
#pragma unroll
    for (int n = 0; n < 4; ++n)
#pragma unroll
        for (int ks = 0; ks < 4; ++ks)
            wr[n][ks] = *reinterpret_cast<const bf16x8*>(
                wencf + (size_t)(((ntg0 + n) * 4 + ks) * 64 + lane) * 8);
    float bias[4];
#pragma unroll
    for (int n = 0; n < 4; ++n) bias[n] = benc[(ntg0 + n) * 16 + (lane & 15)];

#pragma unroll
    for (int i = 0; i < 4; ++i) {
        int c = tid + 256 * i;          // [0,1024): row = c>>4, k8 = c&15
        int row = c >> 4, k8 = c & 15;
        const float* src = x + (size_t)(rid0 + row) * DIN + k8 * 8;
        float4 f0 = *reinterpret_cast<const float4*>(src);
        float4 f1 = *reinterpret_cast<const float4*>(src + 4);
        bf16x8 o;
        o[0] = (__bf16)f0.x; o[1] = (__bf16)f0.y; o[2] = (__bf16)f0.z; o[3] = (__bf16)f0.w;
        o[4] = (__bf16)f1.x; o[5] = (__bf16)f1.y; o[6] = (__bf16)f1.z; o[7] = (__bf16)f1.w;
        int l = (k8 & 3) * 16 + (row & 15);
        int a16 = ((row >> 4) * 4 + (k8 >> 2)) * 64 + l;
        *reinterpret_cast<bf16x8*>(afrag + (size_t)a16 * 8) = o;
    }
    __syncthreads();

    int m = w;
    f32x4 acc[4];
#pragma unroll
    for (int n = 0; n < 4; ++n) acc[n] = (f32x4){bias[n], bias[n], bias[n], bias[n]};
#pragma unroll
    for (int ks = 0; ks < 4; ++ks) {
        bf16x8 a = *reinterpret_cast<const bf16x8*>(afrag + (size_t)((m * 4 + ks) * 64 + lane) * 8);
#pragma unroll
        for (int n = 0; n < 4; ++n)
            acc[n] = __builtin_amdgcn_mfma_f32_16x16x32_bf16(a, wr[n][ks], acc[n], 0, 0, 0);
    }
#pragma unroll
    for (int n = 0; n < 4; ++n) {
        int colg = (ntg0 + n) * 16 + (lane & 15);
#pragma unroll
        for (int q = 0; q < 4; ++q) {
            int rid = rid0 + m * 16 + (lane >> 4) * 4 + q;
            int bb = rid >> 9, tt = rid & 511;
            float th = tanhfast(acc[n][q]);
            enc[(size_t)(tt * BATCH + bb) * DFEAT + colg] = (__bf16)th;
        }
    }
}

// ---------------------------------------------------------------------------
// Persistent LSTM, 16 groups x 16 wgs (r6/r9-proven geometry + LLC protocol).
// Round-10 changes (scheduling only, protocol untouched):
//  1. enc double-buffered prefetch: enc(t+1) loads issue at step top (no
//     waitcnt; in flight across enc-MFMAs + poll + h-load), written to the
//     alternate 8KB LDS buffer after the h-load's vmcnt(0). Removes the
//     enc HBM round-trip AND one barrier from the critical chain (4 -> 3).
//  2. split accumulator chains (even/odd ks) -> MFMA issue fully pipelined.
// LDS: enc buf0 [0,8K), enc buf1 [8K,16K), h frags [16K,32K).
// ---------------------------------------------------------------------------
__global__ __launch_bounds__(256, 1) void lstm_kernel(const __bf16* __restrict__ enc,
                                                      const __bf16* __restrict__ wcat,
                                                      const float* __restrict__ blstm,
                                                      __bf16* __restrict__ hbuf,
                                                      unsigned int* __restrict__ flags) {
    extern __shared__ char smem[];
    __bf16* afrag = reinterpret_cast<__bf16*>(smem);

    int tid = threadIdx.x;
    int lane = tid & 63, np = tid >> 6;     // np = wave; owns 8 h-cols, all gates
    int grp = blockIdx.x & 15, widx = blockIdx.x >> 4;
    int b0 = grp * 16;
    unsigned int* myflag = &flags[(grp * 16 + widx) * 16];

    // persistent weight frags: nf=0 -> [i|f], nf=1 -> [g|o]
    bf16x8 wreg[2][24];
#pragma unroll
    for (int nf = 0; nf < 2; ++nf)
#pragma unroll
        for (int ks = 0; ks < 24; ++ks)
            wreg[nf][ks] = *reinterpret_cast<const bf16x8*>(
                wcat + (size_t)(((((widx * 4 + np) * 2 + nf) * 24) + ks) * 64 + lane) * 8);

    const int cbase = widx * 32 + np * 8 + (lane & 7);
    const bool lo = (lane & 15) < 8;
    const float bias0 = blstm[(lo ? 0 : 1) * 512 + cbase];   // i or f col bias
    const float bias1 = blstm[(lo ? 2 : 3) * 512 + cbase];   // g or o col bias

    // ---- hoisted loop-invariant addresses ----
    // staging coords: row = tid&15, k-base = (tid>>6)*32 + ((tid>>4)&3)*8
    const int srow16 = tid & 15;
    const int kb = (tid >> 6) * 32 + ((tid >> 4) & 3) * 8;
    const __bf16* encp = enc + (size_t)(b0 + srow16) * DFEAT + kb;  // +128 elems = 2nd chunk
    const __bf16* hpA = hbuf + (size_t)(b0 + srow16) * DLAT + kb;   // parity 0; ii -> +128 elems
    const __bf16* hpB = hpA + (size_t)BATCH * DLAT;                 // parity 1
    __bf16* enc_ldsA = afrag + tid * 8;            // buf0 chunk; 2nd at +2048 elems
    __bf16* enc_ldsB = afrag + 4096 + tid * 8;     // buf1
    __bf16* h_lds    = afrag + 8192 + tid * 8;     // h chunk ii=0; +2048 elems per ii
    const __bf16* aencA = afrag + lane * 8;        // + ks*512 elems
    const __bf16* aencB = afrag + 4096 + lane * 8;
    const __bf16* ah    = afrag + 8192 + lane * 8; // + (ks-8)*512 elems

    // h store: thread owns 2 cells (r9-proven pairing via lane^1)
    float c0 = 0.f, c1 = 0.f;
    const int srow = (lane >> 4) * 4 + (lo ? 0 : 2) + (lane & 1);
    const int scol = widx * 32 + np * 8 + (lane & 6);
    unsigned* hdA = reinterpret_cast<unsigned*>(
        hbuf + (size_t)(b0 + srow) * DLAT + scol);                        // parity 0
    unsigned* hdB = reinterpret_cast<unsigned*>(
        hbuf + (size_t)BATCH * DLAT + (size_t)(b0 + srow) * DLAT + scol); // parity 1

    // prologue: stage enc(0) into buf0
    {
        uint4 e0 = *reinterpret_cast<const uint4*>(encp);
        uint4 e1 = *reinterpret_cast<const uint4*>(encp + 128);
        *reinterpret_cast<uint4*>(enc_ldsA) = e0;
        *reinterpret_cast<uint4*>(enc_ldsA + 2048) = e1;
        encp += (size_t)BATCH * DFEAT;
    }
    __syncthreads();

#pragma unroll 1
    for (int t = 0; t < TLEN; ++t) {
        // (0) issue enc(t+1) prefetch -- no waitcnt; flies across this step
        uint4 e0, e1;
        if (t + 1 < TLEN) {
            asm volatile(
                "global_load_dwordx4 %0, %2, off\n\t"
                "global_load_dwordx4 %1, %2, off offset:256"
                : "=&v"(e0), "=&v"(e1)
                : "v"(encp) : "memory");
        }

        // (1) enc-part MFMAs (ks 0..7), split even/odd accumulator chains
        f32x4 acc0e = (f32x4){bias0, bias0, bias0, bias0};
        f32x4 acc1e = (f32x4){bias1, bias1, bias1, bias1};
        f32x4 acc0o = (f32x4){0.f, 0.f, 0.f, 0.f};
        f32x4 acc1o = (f32x4){0.f, 0.f, 0.f, 0.f};
        const __bf16* aenc = (t & 1) ? aencB : aencA;
#pragma unroll
        for (int ks = 0; ks < 8; ks += 2) {
            bf16x8 a0 = *reinterpret_cast<const bf16x8*>(aenc + ks * 512);
            bf16x8 a1 = *reinterpret_cast<const bf16x8*>(aenc + (ks + 1) * 512);
            acc0e = __builtin_amdgcn_mfma_f32_16x16x32_bf16(a0, wreg[0][ks], acc0e, 0, 0, 0);
            acc1e = __builtin_amdgcn_mfma_f32_16x16x32_bf16(a0, wreg[1][ks], acc1e, 0, 0, 0);
            acc0o = __builtin_amdgcn_mfma_f32_16x16x32_bf16(a1, wreg[0][ks + 1], acc0o, 0, 0, 0);
            acc1o = __builtin_amdgcn_mfma_f32_16x16x32_bf16(a1, wreg[1][ks + 1], acc1o, 0, 0, 0);
        }

        if (t > 0) {
            // (2) acquire: wave 0 polls the group's 16 flags (r6-proven)
            if (tid < 64) {
                const unsigned int* f = &flags[(grp * 16 + (lane & 15)) * 16];
                unsigned v;
                do {
                    v = __hip_atomic_load(f, __ATOMIC_RELAXED, __HIP_MEMORY_SCOPE_AGENT);
                } while (!__all((int)(v >= (unsigned)t)));
            }
            __syncthreads();   // b2

            // (3) h(t) slice: 4x16B sc1 loads off one base (+imm offsets)
            const __bf16* hp = (t & 1) ? hpB : hpA;
            uint4 d0, d1, d2, d3;
            asm volatile(
                "global_load_dwordx4 %0, %4, off sc1\n\t"
                "global_load_dwordx4 %1, %4, off offset:256 sc1\n\t"
                "global_load_dwordx4 %2, %4, off offset:512 sc1\n\t"
                "global_load_dwordx4 %3, %4, off offset:768 sc1\n\t"
                "s_waitcnt vmcnt(0)"
                : "=&v"(d0), "=&v"(d1), "=&v"(d2), "=&v"(d3)
                : "v"(hp) : "memory");
            *reinterpret_cast<uint4*>(h_lds) = d0;
            *reinterpret_cast<uint4*>(h_lds + 2048) = d1;
            *reinterpret_cast<uint4*>(h_lds + 4096) = d2;
            *reinterpret_cast<uint4*>(h_lds + 6144) = d3;
        }

        // (4) land enc(t+1) prefetch into the alternate buffer
        asm volatile("s_waitcnt vmcnt(0)" ::: "memory");   // free if (3) ran
        if (t + 1 < TLEN) {
            __bf16* ed = ((t + 1) & 1) ? enc_ldsB : enc_ldsA;
            *reinterpret_cast<uint4*>(ed) = e0;
            *reinterpret_cast<uint4*>(ed + 2048) = e1;
            encp += (size_t)BATCH * DFEAT;
        }
        __syncthreads();   // b3: h frags + next enc visible block-wide

        if (t > 0) {
            // (5) h-part MFMAs (ks 8..23), split chains
#pragma unroll
            for (int ks = 8; ks < 24; ks += 2) {
                bf16x8 a0 = *reinterpret_cast<const bf16x8*>(ah + (ks - 8) * 512);
                bf16x8 a1 = *reinterpret_cast<const bf16x8*>(ah + (ks - 7) * 512);
                acc0e = __builtin_amdgcn_mfma_f32_16x16x32_bf16(a0, wreg[0][ks], acc0e, 0, 0, 0);
                acc1e = __builtin_amdgcn_mfma_f32_16x16x32_bf16(a0, wreg[1][ks], acc1e, 0, 0, 0);
                acc0o = __builtin_amdgcn_mfma_f32_16x16x32_bf16(a1, wreg[0][ks + 1], acc0o, 0, 0, 0);
                acc1o = __builtin_amdgcn_mfma_f32_16x16x32_bf16(a1, wreg[1][ks + 1], acc1o, 0, 0, 0);
            }
        }
        f32x4 z0 = acc0e + acc0o;
        f32x4 z1 = acc1e + acc1o;

        // (6) in-wave gate exchange (r9-proven): lanes cc and cc^8 hold
        // (i,g)/(f,o) for the same cells; shfl_xor(8) delivers all 4 gates.
        float p00 = __shfl_xor(z0[0], 8), p01 = __shfl_xor(z0[1], 8);
        float p02 = __shfl_xor(z0[2], 8), p03 = __shfl_xor(z0[3], 8);
        float p10 = __shfl_xor(z1[0], 8), p11 = __shfl_xor(z1[1], 8);
        float p12 = __shfl_xor(z1[2], 8), p13 = __shfl_xor(z1[3], 8);

        float zi_a = lo ? z0[0] : p02, zf_a = lo ? p00 : z0[2];
        float zg_a = lo ? z1[0] : p12, zo_a = lo ? p10 : z1[2];
        float zi_b = lo ? z0[1] : p03, zf_b = lo ? p01 : z0[3];
        float zg_b = lo ? z1[1] : p13, zo_b = lo ? p11 : z1[3];

        float ia = sigf(zi_a), fa = sigf(zf_a), ga = tanhfast(zg_a), oa = sigf(zo_a);
        c0 = fa * c0 + ia * ga;
        float h_a = oa * tanhfast(c0);
        float ib = sigf(zi_b), fb = sigf(zf_b), gb = tanhfast(zg_b), ob = sigf(zo_b);
        c1 = fb * c1 + ib * gb;
        float h_b = ob * tanhfast(c1);

        // (7) re-pair adjacent columns via lane^1 -> one 4B word per thread
        unsigned sendv = (lane & 1) ? (unsigned)bfb(h_a) : (unsigned)bfb(h_b);
        unsigned recv = (unsigned)__shfl_xor((int)sendv, 1);
        unsigned word = (lane & 1) ? (recv | ((unsigned)bfb(h_b) << 16))
                                   : ((unsigned)bfb(h_a) | (recv << 16));
        __hip_atomic_store(((t & 1) ? hdA : hdB), word, __ATOMIC_RELAXED,
                           __HIP_MEMORY_SCOPE_AGENT);

        // (8) release: __syncthreads drains each wave's vmcnt(0) -> stores
        // LLC-visible; then publish own flag (independent line per wg).
        __syncthreads();   // b4
        if (tid == 0)
            __hip_atomic_store(myflag, (unsigned int)(t + 1), __ATOMIC_RELAXED,
                               __HIP_MEMORY_SCOPE_AGENT);
    }
}

// ---------------------------------------------------------------------------
// Decoder: out[b] = h_last[b,:] @ W_dec + b_dec. h_last is hbuf[0] (T even).
// ---------------------------------------------------------------------------
__global__ __launch_bounds__(64) void dec_kernel(const __bf16* __restrict__ hbuf,
                                                 const float* __restrict__ wdec,
                                                 const float* __restrict__ bdec,
                                                 float* __restrict__ out) {
    int b = blockIdx.x, lane = threadIdx.x;
    uint4 d = *reinterpret_cast<const uint4*>(hbuf + (size_t)b * DLAT + lane * 8);
    const __bf16* hv = reinterpret_cast<const __bf16*>(&d);
    float4 w0 = *reinterpret_cast<const float4*>(wdec + lane * 8);
    float4 w1 = *reinterpret_cast<const float4*>(wdec + lane * 8 + 4);
    float s = (float)hv[0] * w0.x + (float)hv[1] * w0.y + (float)hv[2] * w0.z +
              (float)hv[3] * w0.w + (float)hv[4] * w1.x + (float)hv[5] * w1.y +
              (float)hv[6] * w1.z + (float)hv[7] * w1.w;
#pragma unroll
    for (int off = 32; off; off >>= 1) s += __shfl_xor(s, off);
    if (lane == 0) out[b] = s + bdec[0];
}

extern "C" void kernel_launch(void* const* d_in, const int* in_sizes, int n_in,
                              void* d_out, int out_size, void* d_ws, size_t ws_size,
                              hipStream_t stream) {
    (void)in_sizes; (void)n_in; (void)out_size; (void)ws_size;
    const float* x     = (const float*)d_in[0];
    const float* Wenc  = (const float*)d_in[1];
    const float* benc  = (const float*)d_in[2];
    const float* Wx    = (const float*)d_in[3];
    const float* Wh    = (const float*)d_in[4];
    const float* blstm = (const float*)d_in[5];
    const float* Wdec  = (const float*)d_in[6];
    const float* bdec  = (const float*)d_in[7];

    char* ws = (char*)d_ws;
    __bf16* wcat  = (__bf16*)(ws + WCAT_OFF);
    __bf16* wencf = (__bf16*)(ws + WENC_OFF);
    __bf16* enc   = (__bf16*)(ws + ENC_OFF);
    __bf16* hbuf  = (__bf16*)(ws + H_OFF);
    unsigned int* flags = (unsigned int*)(ws + FLAG_OFF);

    // zero the per-wg flags each call (deterministic across graph replays)
    (void)hipMemsetAsync(ws + FLAG_OFF, 0, 16384, stream);

    wprep_kernel<<<784, 256, 0, stream>>>(Wx, Wh, Wenc, wcat, wencf);
    enc_kernel<<<dim3(2048, 4), 256, 0, stream>>>(x, benc, wencf, enc);

    // 90 KB dynamic LDS forces 1 block/CU (256 blocks on 256 CUs).
    (void)hipFuncSetAttribute(reinterpret_cast<const void*>(lstm_kernel),
                              hipFuncAttributeMaxDynamicSharedMemorySize, 90112);
    lstm_kernel<<<256, 256, 90112, stream>>>(enc, wcat, blstm, hbuf, flags);

    dec_kernel<<<256, 64, 0, stream>>>(hbuf, Wdec, bdec, (float*)d_out);
}

// Round 12
// 1269.931 us; speedup vs baseline: 1.4840x; 1.0023x over previous
//
#include <hip/hip_runtime.h>

// Problem dims
#define BATCH 256
#define TLEN  512
#define DIN   128
#define DFEAT 256
#define DLAT  512
#define G4    2048   // 4*DLAT
#define KCAT  768    // DFEAT + DLAT

typedef __bf16 bf16x8 __attribute__((ext_vector_type(8)));
typedef float f32x4 __attribute__((ext_vector_type(4)));

// ws layout (bytes) -- identical to round 6/9/10 (proven)
#define WCAT_OFF   0u          // 768x2048 bf16 frag-linear: 3,145,728
#define WENC_OFF   3145728u    // 128x256  bf16 frag-linear: 65,536
#define ENC_OFF    3211264u    // enc bf16 [T][B][256]: 67,108,864
#define H_OFF      70320128u   // h dbuf bf16 [2][256][512]: 524,288
#define FLAG_OFF   70844416u   // flags: (grp*16+widx)*16 uints (64B lines): 16,384

__device__ __forceinline__ float sigf(float x)  { return 1.0f / (1.0f + __expf(-x)); }
__device__ __forceinline__ float tanhfast(float x){ return 2.0f / (1.0f + __expf(-2.0f * x)) - 1.0f; }
__device__ __forceinline__ unsigned short bfb(float f) {
    __bf16 b = (__bf16)f;
    return __builtin_bit_cast(unsigned short, b);
}

// ---------------------------------------------------------------------------
// Weight prep: bf16 fragment-linear copies of [W_x;W_h] (768x2048) and W_enc.
// wcat layout (wave-owns-all-gates, r9-proven): chunk cid = ((((widx*4 + np)
// *2 + nf)*24 + ks)*64 + l) holds B[k = ks*32+(l>>4)*8 .. +8][col] with
//   cc = l&15;  gate = (cc<8) ? (nf?2:0) : (nf?3:1);
//   col = gate*512 + widx*32 + np*8 + (cc&7).
// ---------------------------------------------------------------------------
__global__ __launch_bounds__(256) void wprep_kernel(const float* __restrict__ Wx,
                                                    const float* __restrict__ Wh,
                                                    const float* __restrict__ Wenc,
                                                    __bf16* __restrict__ wcat,
                                                    __bf16* __restrict__ wencf) {
    int cid = blockIdx.x * 256 + threadIdx.x;   // 200704 total
    float v[8];
    __bf16* dst;
    if (cid < 196608) {
        int widx = cid / 12288;      // 16 wgs
        int r1 = cid % 12288;
        int nn = r1 / 1536;          // np*2 + nf, 0..7
        int r2 = r1 % 1536;
        int ks = r2 >> 6, l = r2 & 63;
        int np = nn >> 1, nf = nn & 1;
        int cc = l & 15;
        int gate = (cc < 8) ? (nf ? 2 : 0) : (nf ? 3 : 1);
        int col = gate * 512 + widx * 32 + np * 8 + (cc & 7);
        int kc = ks * 32 + (l >> 4) * 8;
#pragma unroll
        for (int j = 0; j < 8; ++j) {
            int kk = kc + j;
            v[j] = (kk < DFEAT) ? Wx[kk * G4 + col] : Wh[(kk - DFEAT) * G4 + col];
        }
        dst = wcat + (size_t)cid * 8;
    } else {
        int c2 = cid - 196608;   // [0, 4096)
        int ntg = c2 >> 8;
        int r = c2 & 255;
        int ks = r >> 6, l = r & 63;
        int col = ntg * 16 + (l & 15);
        int kc = ks * 32 + (l >> 4) * 8;
#pragma unroll
        for (int j = 0; j < 8; ++j) v[j] = Wenc[(kc + j) * DFEAT + col];
        dst = wencf + (size_t)c2 * 8;
    }
    bf16x8 o;
#pragma unroll
    for (int j = 0; j < 8; ++j) o[j] = (__bf16)v[j];
    *reinterpret_cast<bf16x8*>(dst) = o;
}

// ---------------------------------------------------------------------------
// Encoder: enc[t][b][f] = tanh(x[b][t][:] @ W_enc + b_enc), bf16 out.
// ---------------------------------------------------------------------------
__global__ __launch_bounds__(256) void enc_kernel(const float* __restrict__ x,
                                                  const float* __restrict__ benc,
                                                  const __bf16* __restrict__ wencf,
                                                  __bf16* __restrict__ enc) {
    __shared__ uint4 afrag4[1024];   // 16 KB frag-linear A
    __bf16* afrag = reinterpret_cast<__bf16*>(afrag4);
    int tid = threadIdx.x;
    int lane = tid & 63, w = tid >> 6;
    int rid0 = blockIdx.x * 64;
    int ntg0 = blockIdx.y * 4;

    bf16x8 wr[4][4];
#pragma unroll
    for (int n = 0; n < 4; ++n)
#pragma unroll
        for (int ks = 0; ks < 4; ++ks)
            wr[n][ks] = *reinterpret_cast<const bf16x8*>(
                wencf + (size_t)(((ntg0 + n) * 4 + ks) * 64 + lane) * 8);
    float bias[4];
#pragma unroll
    for (int n = 0; n < 4; ++n) bias[n] = benc[(ntg0 + n) * 16 + (lane & 15)];

#pragma unroll
    for (int i = 0; i < 4; ++i) {
        int c = tid + 256 * i;          // [0,1024): row = c>>4, k8 = c&15
        int row = c >> 4, k8 = c & 15;
        const float* src = x + (size_t)(rid0 + row) * DIN + k8 * 8;
        float4 f0 = *reinterpret_cast<const float4*>(src);
        float4 f1 = *reinterpret_cast<const float4*>(src + 4);
        bf16x8 o;
        o[0] = (__bf16)f0.x; o[1] = (__bf16)f0.y; o[2] = (__bf16)f0.z; o[3] = (__bf16)f0.w;
        o[4] = (__bf16)f1.x; o[5] = (__bf16)f1.y; o[6] = (__bf16)f1.z; o[7] = (__bf16)f1.w;
        int l = (k8 & 3) * 16 + (row & 15);
        int a16 = ((row >> 4) * 4 + (k8 >> 2)) * 64 + l;
        *reinterpret_cast<bf16x8*>(afrag + (size_t)a16 * 8) = o;
    }
    __syncthreads();

    int m = w;
    f32x4 acc[4];
#pragma unroll
    for (int n = 0; n < 4; ++n) acc[n] = (f32x4){bias[n], bias[n], bias[n], bias[n]};
#pragma unroll
    for (int ks = 0; ks < 4; ++ks) {
        bf16x8 a = *reinterpret_cast<const bf16x8*>(afrag + (size_t)((m * 4 + ks) * 64 + lane) * 8);
#pragma unroll
        for (int n = 0; n < 4; ++n)
            acc[n] = __builtin_amdgcn_mfma_f32_16x16x32_bf16(a, wr[n][ks], acc[n], 0, 0, 0);
    }
#pragma unroll
    for (int n = 0; n < 4; ++n) {
        int colg = (ntg0 + n) * 16 + (lane & 15);
#pragma unroll
        for (int q = 0; q < 4; ++q) {
            int rid = rid0 + m * 16 + (lane >> 4) * 4 + q;
            int bb = rid >> 9, tt = rid & 511;
            float th = tanhfast(acc[n][q]);
            enc[(size_t)(tt * BATCH + bb) * DFEAT + colg] = (__bf16)th;
        }
    }
}

// ---------------------------------------------------------------------------
// Persistent LSTM, 16 groups x 16 wgs -- r10 base (proven 1273us), with ONE
// change: coalesced 8B h-stores (lanes l, l^2 hold adjacent 4B of the same
// row; one extra shfl_xor(2) assembles 8B; lanes with lane&2==0 store via
// the r5-proven u64 relaxed-agent primitive). Halves store requests and
// restores write coalescing (r9 regression: WRITE_SIZE 135->266MB).
//
// NOTE (r3, r11 post-mortems): per-XCD L2 (sc0) exchange is NOT a usable
// software coherence point on gfx950 -- two independent attempts produced a
// hang (r3) and stale-data corruption (r11). All inter-block exchange stays
// on the verified relaxed-agent/sc1 LLC protocol.
// ---------------------------------------------------------------------------
__global__ __launch_bounds__(256, 1) void lstm_kernel(const __bf16* __restrict__ enc,
                                                      const __bf16* __restrict__ wcat,
                                                      const float* __restrict__ blstm,
                                                      __bf16* __restrict__ hbuf,
                                                      unsigned int* __restrict__ flags) {
    extern __shared__ char smem[];
    __bf16* afrag = reinterpret_cast<__bf16*>(smem);

    int tid = threadIdx.x;
    int lane = tid & 63, np = tid >> 6;     // np = wave; owns 8 h-cols, all gates
    int grp = blockIdx.x & 15, widx = blockIdx.x >> 4;
    int b0 = grp * 16;
    unsigned int* myflag = &flags[(grp * 16 + widx) * 16];

    // persistent weight frags: nf=0 -> [i|f], nf=1 -> [g|o]
    bf16x8 wreg[2][24];
#pragma unroll
    for (int nf = 0; nf < 2; ++nf)
#pragma unroll
        for (int ks = 0; ks < 24; ++ks)
            wreg[nf][ks] = *reinterpret_cast<const bf16x8*>(
                wcat + (size_t)(((((widx * 4 + np) * 2 + nf) * 24) + ks) * 64 + lane) * 8);

    const int cbase = widx * 32 + np * 8 + (lane & 7);
    const bool lo = (lane & 15) < 8;
    const float bias0 = blstm[(lo ? 0 : 1) * 512 + cbase];   // i or f col bias
    const float bias1 = blstm[(lo ? 2 : 3) * 512 + cbase];   // g or o col bias

    // ---- hoisted loop-invariant addresses (r10) ----
    const int srow16 = tid & 15;
    const int kb = (tid >> 6) * 32 + ((tid >> 4) & 3) * 8;
    const __bf16* encp = enc + (size_t)(b0 + srow16) * DFEAT + kb;
    const __bf16* hpA = hbuf + (size_t)(b0 + srow16) * DLAT + kb;   // parity 0
    const __bf16* hpB = hpA + (size_t)BATCH * DLAT;                 // parity 1
    __bf16* enc_ldsA = afrag + tid * 8;            // buf0 chunk; 2nd at +2048 elems
    __bf16* enc_ldsB = afrag + 4096 + tid * 8;     // buf1
    __bf16* h_lds    = afrag + 8192 + tid * 8;     // h chunk ii=0; +2048 elems per ii
    const __bf16* aencA = afrag + lane * 8;        // + ks*512 elems
    const __bf16* aencB = afrag + 4096 + lane * 8;
    const __bf16* ah    = afrag + 8192 + lane * 8; // + (ks-8)*512 elems

    // h store: lanes l,l^2 hold adjacent 4B of row srow (srow ignores bit1);
    // lane&2==0 lanes store 8B at col scol8 (r12 coalescing change)
    float c0 = 0.f, c1 = 0.f;
    const int srow = (lane >> 4) * 4 + (lo ? 0 : 2) + (lane & 1);
    const int scol8 = widx * 32 + np * 8 + (lane & 4);
    unsigned long long* hdA8 = reinterpret_cast<unsigned long long*>(
        hbuf + (size_t)(b0 + srow) * DLAT + scol8);                        // parity 0
    unsigned long long* hdB8 = reinterpret_cast<unsigned long long*>(
        hbuf + (size_t)BATCH * DLAT + (size_t)(b0 + srow) * DLAT + scol8); // parity 1

    // prologue: stage enc(0) into buf0
    {
        uint4 e0 = *reinterpret_cast<const uint4*>(encp);
        uint4 e1 = *reinterpret_cast<const uint4*>(encp + 128);
        *reinterpret_cast<uint4*>(enc_ldsA) = e0;
        *reinterpret_cast<uint4*>(enc_ldsA + 2048) = e1;
        encp += (size_t)BATCH * DFEAT;
    }
    __syncthreads();

#pragma unroll 1
    for (int t = 0; t < TLEN; ++t) {
        // (0) issue enc(t+1) prefetch -- no waitcnt; flies across this step
        uint4 e0, e1;
        if (t + 1 < TLEN) {
            asm volatile(
                "global_load_dwordx4 %0, %2, off\n\t"
                "global_load_dwordx4 %1, %2, off offset:256"
                : "=&v"(e0), "=&v"(e1)
                : "v"(encp) : "memory");
        }

        // (1) enc-part MFMAs (ks 0..7), split even/odd accumulator chains
        f32x4 acc0e = (f32x4){bias0, bias0, bias0, bias0};
        f32x4 acc1e = (f32x4){bias1, bias1, bias1, bias1};
        f32x4 acc0o = (f32x4){0.f, 0.f, 0.f, 0.f};
        f32x4 acc1o = (f32x4){0.f, 0.f, 0.f, 0.f};
        const __bf16* aenc = (t & 1) ? aencB : aencA;
#pragma unroll
        for (int ks = 0; ks < 8; ks += 2) {
            bf16x8 a0 = *reinterpret_cast<const bf16x8*>(aenc + ks * 512);
            bf16x8 a1 = *reinterpret_cast<const bf16x8*>(aenc + (ks + 1) * 512);
            acc0e = __builtin_amdgcn_mfma_f32_16x16x32_bf16(a0, wreg[0][ks], acc0e, 0, 0, 0);
            acc1e = __builtin_amdgcn_mfma_f32_16x16x32_bf16(a0, wreg[1][ks], acc1e, 0, 0, 0);
            acc0o = __builtin_amdgcn_mfma_f32_16x16x32_bf16(a1, wreg[0][ks + 1], acc0o, 0, 0, 0);
            acc1o = __builtin_amdgcn_mfma_f32_16x16x32_bf16(a1, wreg[1][ks + 1], acc1o, 0, 0, 0);
        }

        if (t > 0) {
            // (2) acquire: wave 0 polls the group's 16 flags (r6-proven)
            if (tid < 64) {
                const unsigned int* f = &flags[(grp * 16 + (lane & 15)) * 16];
                unsigned v;
                do {
                    v = __hip_atomic_load(f, __ATOMIC_RELAXED, __HIP_MEMORY_SCOPE_AGENT);
                } while (!__all((int)(v >= (unsigned)t)));
            }
            __syncthreads();   // b2

            // (3) h(t) slice: 4x16B sc1 loads off one base (+imm offsets)
            const __bf16* hp = (t & 1) ? hpB : hpA;
            uint4 d0, d1, d2, d3;
            asm volatile(
                "global_load_dwordx4 %0, %4, off sc1\n\t"
                "global_load_dwordx4 %1, %4, off offset:256 sc1\n\t"
                "global_load_dwordx4 %2, %4, off offset:512 sc1\n\t"
                "global_load_dwordx4 %3, %4, off offset:768 sc1\n\t"
                "s_waitcnt vmcnt(0)"
                : "=&v"(d0), "=&v"(d1), "=&v"(d2), "=&v"(d3)
                : "v"(hp) : "memory");
            *reinterpret_cast<uint4*>(h_lds) = d0;
            *reinterpret_cast<uint4*>(h_lds + 2048) = d1;
            *reinterpret_cast<uint4*>(h_lds + 4096) = d2;
            *reinterpret_cast<uint4*>(h_lds + 6144) = d3;
        }

        // (4) land enc(t+1) prefetch into the alternate buffer
        asm volatile("s_waitcnt vmcnt(0)" ::: "memory");   // free if (3) ran
        if (t + 1 < TLEN) {
            __bf16* ed = ((t + 1) & 1) ? enc_ldsB : enc_ldsA;
            *reinterpret_cast<uint4*>(ed) = e0;
            *reinterpret_cast<uint4*>(ed + 2048) = e1;
            encp += (size_t)BATCH * DFEAT;
        }
        __syncthreads();   // b3: h frags + next enc visible block-wide

        if (t > 0) {
            // (5) h-part MFMAs (ks 8..23), split chains
#pragma unroll
            for (int ks = 8; ks < 24; ks += 2) {
                bf16x8 a0 = *reinterpret_cast<const bf16x8*>(ah + (ks - 8) * 512);
                bf16x8 a1 = *reinterpret_cast<const bf16x8*>(ah + (ks - 7) * 512);
                acc0e = __builtin_amdgcn_mfma_f32_16x16x32_bf16(a0, wreg[0][ks], acc0e, 0, 0, 0);
                acc1e = __builtin_amdgcn_mfma_f32_16x16x32_bf16(a0, wreg[1][ks], acc1e, 0, 0, 0);
                acc0o = __builtin_amdgcn_mfma_f32_16x16x32_bf16(a1, wreg[0][ks + 1], acc0o, 0, 0, 0);
                acc1o = __builtin_amdgcn_mfma_f32_16x16x32_bf16(a1, wreg[1][ks + 1], acc1o, 0, 0, 0);
            }
        }
        f32x4 z0 = acc0e + acc0o;
        f32x4 z1 = acc1e + acc1o;

        // (6) in-wave gate exchange (r9-proven)
        float p00 = __shfl_xor(z0[0], 8), p01 = __shfl_xor(z0[1], 8);
        float p02 = __shfl_xor(z0[2], 8), p03 = __shfl_xor(z0[3], 8);
        float p10 = __shfl_xor(z1[0], 8), p11 = __shfl_xor(z1[1], 8);
        float p12 = __shfl_xor(z1[2], 8), p13 = __shfl_xor(z1[3], 8);

        float zi_a = lo ? z0[0] : p02, zf_a = lo ? p00 : z0[2];
        float zg_a = lo ? z1[0] : p12, zo_a = lo ? p10 : z1[2];
        float zi_b = lo ? z0[1] : p03, zf_b = lo ? p01 : z0[3];
        float zg_b = lo ? z1[1] : p13, zo_b = lo ? p11 : z1[3];

        float ia = sigf(zi_a), fa = sigf(zf_a), ga = tanhfast(zg_a), oa = sigf(zo_a);
        c0 = fa * c0 + ia * ga;
        float h_a = oa * tanhfast(c0);
        float ib = sigf(zi_b), fb = sigf(zf_b), gb = tanhfast(zg_b), ob = sigf(zo_b);
        c1 = fb * c1 + ib * gb;
        float h_b = ob * tanhfast(c1);

        // (7) re-pair adjacent columns via lane^1 (r9-proven), then assemble
        // 8B per lane-pair via lane^2 (same row: srow ignores bit1) and store
        // from lanes with lane&2==0 -- r5-proven u64 relaxed-agent primitive.
        unsigned sendv = (lane & 1) ? (unsigned)bfb(h_a) : (unsigned)bfb(h_b);
        unsigned recv = (unsigned)__shfl_xor((int)sendv, 1);
        unsigned word = (lane & 1) ? (recv | ((unsigned)bfb(h_b) << 16))
                                   : ((unsigned)bfb(h_a) | (recv << 16));
        unsigned word2 = (unsigned)__shfl_xor((int)word, 2);
        if ((lane & 2) == 0) {
            unsigned long long w8 =
                (unsigned long long)word | ((unsigned long long)word2 << 32);
            __hip_atomic_store(((t & 1) ? hdA8 : hdB8), w8, __ATOMIC_RELAXED,
                               __HIP_MEMORY_SCOPE_AGENT);
        }

        // (8) release: __syncthreads drains each wave's vmcnt(0) -> stores
        // LLC-visible; then publish own flag (independent line per wg).
        __syncthreads();   // b4
        if (tid == 0)
            __hip_atomic_store(myflag, (unsigned int)(t + 1), __ATOMIC_RELAXED,
                               __HIP_MEMORY_SCOPE_AGENT);
    }
}

// ---------------------------------------------------------------------------
// Decoder: out[b] = h_last[b,:] @ W_dec + b_dec. h_last is hbuf[0] (T even).
// ---------------------------------------------------------------------------
__global__ __launch_bounds__(64) void dec_kernel(const __bf16* __restrict__ hbuf,
                                                 const float* __restrict__ wdec,
                                                 const float* __restrict__ bdec,
                                                 float* __restrict__ out) {
    int b = blockIdx.x, lane = threadIdx.x;
    uint4 d = *reinterpret_cast<const uint4*>(hbuf + (size_t)b * DLAT + lane * 8);
    const __bf16* hv = reinterpret_cast<const __bf16*>(&d);
    float4 w0 = *reinterpret_cast<const float4*>(wdec + lane * 8);
    float4 w1 = *reinterpret_cast<const float4*>(wdec + lane * 8 + 4);
    float s = (float)hv[0] * w0.x + (float)hv[1] * w0.y + (float)hv[2] * w0.z +
              (float)hv[3] * w0.w + (float)hv[4] * w1.x + (float)hv[5] * w1.y +
              (float)hv[6] * w1.z + (float)hv[7] * w1.w;
#pragma unroll
    for (int off = 32; off; off >>= 1) s += __shfl_xor(s, off);
    if (lane == 0) out[b] = s + bdec[0];
}

extern "C" void kernel_launch(void* const* d_in, const int* in_sizes, int n_in,
                              void* d_out, int out_size, void* d_ws, size_t ws_size,
                              hipStream_t stream) {
    (void)in_sizes; (void)n_in; (void)out_size; (void)ws_size;
    const float* x     = (const float*)d_in[0];
    const float* Wenc  = (const float*)d_in[1];
    const float* benc  = (const float*)d_in[2];
    const float* Wx    = (const float*)d_in[3];
    const float* Wh    = (const float*)d_in[4];
    const float* blstm = (const float*)d_in[5];
    const float* Wdec  = (const float*)d_in[6];
    const float* bdec  = (const float*)d_in[7];

    char* ws = (char*)d_ws;
    __bf16* wcat  = (__bf16*)(ws + WCAT_OFF);
    __bf16* wencf = (__bf16*)(ws + WENC_OFF);
    __bf16* enc   = (__bf16*)(ws + ENC_OFF);
    __bf16* hbuf  = (__bf16*)(ws + H_OFF);
    unsigned int* flags = (unsigned int*)(ws + FLAG_OFF);

    // zero the per-wg flags each call (deterministic across graph replays)
    (void)hipMemsetAsync(ws + FLAG_OFF, 0, 16384, stream);

    wprep_kernel<<<784, 256, 0, stream>>>(Wx, Wh, Wenc, wcat, wencf);
    enc_kernel<<<dim3(2048, 4), 256, 0, stream>>>(x, benc, wencf, enc);

    // 90 KB dynamic LDS forces 1 block/CU (256 blocks on 256 CUs).
    (void)hipFuncSetAttribute(reinterpret_cast<const void*>(lstm_kernel),
                              hipFuncAttributeMaxDynamicSharedMemorySize, 90112);
    lstm_kernel<<<256, 256, 90112, stream>>>(enc, wcat, blstm, hbuf, flags);

    dec_kernel<<<256, 64, 0, stream>>>(hbuf, Wdec, bdec, (float*)d_out);
}